// Round 3
// baseline (5109.887 us; speedup 1.0000x reference)
//
#include <hip/hip_runtime.h>
#include <hip/hip_bf16.h>

typedef __hip_bfloat16 bf16;
typedef __attribute__((ext_vector_type(8))) short short8;   // 8 bf16 (4 VGPRs)
typedef __attribute__((ext_vector_type(4))) float f32x4;

constexpr int D     = 1024;
constexpr int T     = 2048;
constexpr int BATCH = 2;
constexpr int ROWS  = BATCH * T;   // 4096
constexpr int NH    = 16;
constexpr int DKEY  = 64;
constexpr int QKVN  = 3 * D;       // 3072
constexpr int FFNN  = 4 * D;       // 4096

static __device__ __forceinline__ float b2f(bf16 x) { return __bfloat162float(x); }
static __device__ __forceinline__ bf16  f2b(float x) { return __float2bfloat16(x); }
static __device__ __forceinline__ float loadf(const bf16* p)  { return __bfloat162float(*p); }
static __device__ __forceinline__ float loadf(const float* p) { return *p; }

// ---------- fp32 [R][C] -> bf16 [C][R] transpose + downcast ----------
__global__ __launch_bounds__(256) void transpose_cast(const float* __restrict__ in,
                                                      bf16* __restrict__ out,
                                                      int R, int C)
{
    __shared__ float tile[32][33];
    int c0 = blockIdx.x * 32, r0 = blockIdx.y * 32;
    int tx = threadIdx.x & 31, ty = threadIdx.x >> 5;  // 8 rows per pass
#pragma unroll
    for (int i = 0; i < 32; i += 8)
        tile[ty + i][tx] = in[(size_t)(r0 + ty + i) * C + c0 + tx];
    __syncthreads();
#pragma unroll
    for (int i = 0; i < 32; i += 8)
        out[(size_t)(c0 + ty + i) * R + r0 + tx] = f2b(tile[tx][ty + i]);
}

// ---------- LayerNorm: one block per row of 1024, fp32 gamma/beta, bf16 out ----------
template <typename TIN>
__global__ __launch_bounds__(256) void ln_kernel(const TIN* __restrict__ X,
                                                 const float* __restrict__ g,
                                                 const float* __restrict__ b,
                                                 bf16* __restrict__ out)
{
    int row = blockIdx.x;
    int tid = threadIdx.x;
    const TIN* xr = X + (size_t)row * D;
    float v[4];
#pragma unroll
    for (int i = 0; i < 4; ++i) v[i] = loadf(xr + tid + i * 256);

    float s1 = v[0] + v[1] + v[2] + v[3];
    float s2 = v[0]*v[0] + v[1]*v[1] + v[2]*v[2] + v[3]*v[3];
#pragma unroll
    for (int off = 32; off; off >>= 1) {
        s1 += __shfl_xor(s1, off);
        s2 += __shfl_xor(s2, off);
    }
    __shared__ float red[8];
    int lane = tid & 63, w = tid >> 6;
    if (lane == 0) { red[w] = s1; red[4 + w] = s2; }
    __syncthreads();
    s1 = red[0] + red[1] + red[2] + red[3];
    s2 = red[4] + red[5] + red[6] + red[7];

    float mu   = s1 * (1.0f / D);
    float var  = s2 * (1.0f / D) - mu * mu;
    float rstd = rsqrtf(var + 1e-5f);

    bf16* orow = out + (size_t)row * D;
#pragma unroll
    for (int i = 0; i < 4; ++i) {
        int c = tid + i * 256;
        orow[c] = f2b((v[i] - mu) * rstd * g[c] + b[c]);
    }
}

// ---------- MFMA GEMM: out[M][N] = A[M][K](bf16) @ Bt[N][K](bf16)^T + bias (+relu)(+resid) ----------
// RES: 0 none, 1 bf16 resid, 2 fp32 resid. OUTF32: write fp32 (else bf16).
// Tiles: block 128x128, BK=32, 4 waves in 2x2.
// mfma_f32_16x16x32_bf16 layouts (m89/m91/m120-verified):
//   A: m=lane&15, k=quad*8+j   B: k=quad*8+j, n=lane&15   C/D: row=quad*4+r, col=lane&15
template <int RELU, int RES, int OUTF32>
__global__ __launch_bounds__(256) void mfma_gemm(
    const bf16* __restrict__ A, const bf16* __restrict__ Bt,
    const float* __restrict__ bias, const void* __restrict__ resid,
    void* __restrict__ out, int M, int N, int K)
{
    constexpr int LDSK = 40;  // 32 + 8 pad: 80B row stride, 16B-aligned, breaks pow2 banking
    __shared__ __align__(16) unsigned short As[128 * LDSK];
    __shared__ __align__(16) unsigned short Bs[128 * LDSK];

    int tid  = threadIdx.x;
    int m0   = blockIdx.y * 128, n0 = blockIdx.x * 128;
    int lane = tid & 63, wave = tid >> 6;
    int wm = (wave >> 1) * 64, wn = (wave & 1) * 64;
    int c15 = lane & 15, quad = lane >> 4;

    f32x4 acc[4][4] = {};

    int srow = tid >> 1, shalf = tid & 1;  // staging: 128 rows x two 16-elem halves
    const bf16* aptr = A  + (size_t)(m0 + srow) * K + shalf * 16;
    const bf16* bptr = Bt + (size_t)(n0 + srow) * K + shalf * 16;
    unsigned short* asl = &As[srow * LDSK + shalf * 16];
    unsigned short* bsl = &Bs[srow * LDSK + shalf * 16];

    for (int k0 = 0; k0 < K; k0 += 32) {
        uint4 a0 = *(const uint4*)(aptr + k0);
        uint4 a1 = *(const uint4*)(aptr + k0 + 8);
        uint4 b0 = *(const uint4*)(bptr + k0);
        uint4 b1 = *(const uint4*)(bptr + k0 + 8);
        __syncthreads();                    // prev iter's LDS reads complete
        *(uint4*)asl       = a0;
        *(uint4*)(asl + 8) = a1;
        *(uint4*)bsl       = b0;
        *(uint4*)(bsl + 8) = b1;
        __syncthreads();

        short8 af[4], bfr[4];
#pragma unroll
        for (int t = 0; t < 4; ++t)
            af[t]  = *(const short8*)&As[(wm + t * 16 + c15) * LDSK + quad * 8];
#pragma unroll
        for (int t = 0; t < 4; ++t)
            bfr[t] = *(const short8*)&Bs[(wn + t * 16 + c15) * LDSK + quad * 8];
#pragma unroll
        for (int mt = 0; mt < 4; ++mt)
#pragma unroll
            for (int nt = 0; nt < 4; ++nt)
                acc[mt][nt] = __builtin_amdgcn_mfma_f32_16x16x32_bf16(
                    af[mt], bfr[nt], acc[mt][nt], 0, 0, 0);
    }

#pragma unroll
    for (int mt = 0; mt < 4; ++mt) {
#pragma unroll
        for (int nt = 0; nt < 4; ++nt) {
            f32x4 v4 = acc[mt][nt];
            int gc = n0 + wn + nt * 16 + c15;
            float bb = bias[gc];
#pragma unroll
            for (int r = 0; r < 4; ++r) {
                int gr = m0 + wm + mt * 16 + quad * 4 + r;
                float v = v4[r] + bb;
                if constexpr (RELU) v = fmaxf(v, 0.0f);
                size_t idx = (size_t)gr * N + gc;
                if constexpr (RES == 1) v += b2f(((const bf16*)resid)[idx]);
                if constexpr (RES == 2) v += ((const float*)resid)[idx];
                if constexpr (OUTF32) ((float*)out)[idx] = v;
                else                  ((bf16*)out)[idx] = f2b(v);
            }
        }
    }
}

// ---------- Causal attention: one wave per query row, online softmax ----------
__global__ __launch_bounds__(256) void attn_kernel(const bf16* __restrict__ qkv,
                                                   bf16* __restrict__ ctx)
{
    int wid  = (blockIdx.x << 2) | (threadIdx.x >> 6);
    int lane = threadIdx.x & 63;
    int q  = wid & (T - 1);
    int bh = wid >> 11;
    int h  = bh & (NH - 1);
    int b  = bh >> 4;

    const bf16* base = qkv + (size_t)b * T * QKVN;
    float qd = b2f(base[(size_t)q * QKVN + h * DKEY + lane]) * 0.125f;  // 1/sqrt(64)
    const bf16* Kp = base + D     + h * DKEY + lane;
    const bf16* Vp = base + 2 * D + h * DKEY + lane;

    float m = -1e30f, l = 0.0f, o = 0.0f;
    for (int j = 0; j <= q; ++j) {
        float kd = b2f(Kp[(size_t)j * QKVN]);
        float vd = b2f(Vp[(size_t)j * QKVN]);
        float s = qd * kd;
#pragma unroll
        for (int off = 32; off; off >>= 1) s += __shfl_xor(s, off);
        float mn = fmaxf(m, s);
        float p  = __expf(s - mn);
        float al = __expf(m - mn);
        l = l * al + p;
        o = o * al + p * vd;
        m = mn;
    }
    ctx[(size_t)(b * T + q) * D + h * DKEY + lane] = f2b(o / l);
}

extern "C" void kernel_launch(void* const* d_in, const int* in_sizes, int n_in,
                              void* d_out, int out_size, void* d_ws, size_t ws_size,
                              hipStream_t stream)
{
    const float* X    = (const float*)d_in[0];
    const float* Wqkv = (const float*)d_in[1];
    const float* bqkv = (const float*)d_in[2];
    const float* Wo   = (const float*)d_in[3];
    const float* bo   = (const float*)d_in[4];
    const float* W1   = (const float*)d_in[5];
    const float* b1   = (const float*)d_in[6];
    const float* W2   = (const float*)d_in[7];
    const float* b2   = (const float*)d_in[8];
    const float* ln1g = (const float*)d_in[9];
    const float* ln1b = (const float*)d_in[10];
    const float* ln2g = (const float*)d_in[11];
    const float* ln2b = (const float*)d_in[12];
    float* out = (float*)d_out;   // reference output dtype is float32

    // Workspace (peak 72 MiB):
    char* ws = (char*)d_ws;
    bf16* Wqkv_t = (bf16*)(ws + 0);          // [3072][1024]  6 MiB
    bf16* Wo_t   = (bf16*)(ws + 6291456);    // [1024][1024]  2 MiB
    bf16* W1_t   = (bf16*)(ws + 8388608);    // [4096][1024]  8 MiB
    bf16* W2_t   = (bf16*)(ws + 16777216);   // [1024][4096]  8 MiB
    bf16* Xn     = (bf16*)(ws + 25165824);   // 8 MiB; slot reused by X1 after step 2
    bf16* X1     = Xn;
    bf16* qkv    = (bf16*)(ws + 33554432);   // 24 MiB; first 8 MiB reused by Xn2 after attn
    bf16* Xn2    = (bf16*)(ws + 33554432);
    bf16* ctx    = (bf16*)(ws + 58720256);   // 8 MiB
    bf16* mid    = (bf16*)(ws + 41943040);   // 32 MiB over dead qkv-tail+ctx; ends at 72 MiB

    // 0) weights: fp32 -> bf16, transposed to [N][K]
    transpose_cast<<<dim3(QKVN / 32, D / 32), 256, 0, stream>>>(Wqkv, Wqkv_t, D, QKVN);
    transpose_cast<<<dim3(D / 32, D / 32), 256, 0, stream>>>(Wo, Wo_t, D, D);
    transpose_cast<<<dim3(FFNN / 32, D / 32), 256, 0, stream>>>(W1, W1_t, D, FFNN);
    transpose_cast<<<dim3(D / 32, FFNN / 32), 256, 0, stream>>>(W2, W2_t, FFNN, D);
    // 1) Xn = LN1(X)
    ln_kernel<float><<<ROWS, 256, 0, stream>>>(X, ln1g, ln1b, Xn);
    // 2) qkv = Xn @ Wqkv + bqkv
    mfma_gemm<0, 0, 0><<<dim3(QKVN / 128, ROWS / 128), 256, 0, stream>>>(
        Xn, Wqkv_t, bqkv, nullptr, qkv, ROWS, QKVN, D);
    // 3) ctx = causal-softmax(q k^T / 8) v
    attn_kernel<<<(BATCH * NH * T) / 4, 256, 0, stream>>>(qkv, ctx);
    // 4) X1 = X + ctx @ Wo + bo
    mfma_gemm<0, 2, 0><<<dim3(D / 128, ROWS / 128), 256, 0, stream>>>(
        ctx, Wo_t, bo, X, X1, ROWS, D, D);
    // 5) Xn2 = LN2(X1)
    ln_kernel<bf16><<<ROWS, 256, 0, stream>>>(X1, ln2g, ln2b, Xn2);
    // 6) mid = relu(Xn2 @ W1 + b1)
    mfma_gemm<1, 0, 0><<<dim3(FFNN / 128, ROWS / 128), 256, 0, stream>>>(
        Xn2, W1_t, b1, nullptr, mid, ROWS, FFNN, D);
    // 7) out = X1 + mid @ W2 + b2   (fp32 output)
    mfma_gemm<0, 1, 1><<<dim3(D / 128, ROWS / 128), 256, 0, stream>>>(
        mid, W2_t, b2, X1, out, ROWS, D, FFNN);
}

// Round 5
// 461.987 us; speedup vs baseline: 11.0607x; 11.0607x over previous
//
#include <hip/hip_runtime.h>
#include <hip/hip_bf16.h>

typedef __hip_bfloat16 bf16;
typedef __attribute__((ext_vector_type(8))) short short8;   // 8 bf16 (4 VGPRs)
typedef __attribute__((ext_vector_type(4))) float f32x4;

constexpr int D     = 1024;
constexpr int T     = 2048;
constexpr int BATCH = 2;
constexpr int ROWS  = BATCH * T;   // 4096
constexpr int NH    = 16;
constexpr int DKEY  = 64;
constexpr int QKVN  = 3 * D;       // 3072
constexpr int FFNN  = 4 * D;       // 4096

static __device__ __forceinline__ float b2f(bf16 x) { return __bfloat162float(x); }
static __device__ __forceinline__ bf16  f2b(float x) { return __float2bfloat16(x); }
static __device__ __forceinline__ float loadf(const bf16* p)  { return __bfloat162float(*p); }
static __device__ __forceinline__ float loadf(const float* p) { return *p; }
static __device__ __forceinline__ float fast_exp2(float x) { return __builtin_amdgcn_exp2f(x); }

// ---------- fp32 [R][C] -> bf16 [C][R] transpose + downcast ----------
__global__ __launch_bounds__(256) void transpose_cast(const float* __restrict__ in,
                                                      bf16* __restrict__ out,
                                                      int R, int C)
{
    __shared__ float tile[32][33];
    int c0 = blockIdx.x * 32, r0 = blockIdx.y * 32;
    int tx = threadIdx.x & 31, ty = threadIdx.x >> 5;  // 8 rows per pass
#pragma unroll
    for (int i = 0; i < 32; i += 8)
        tile[ty + i][tx] = in[(size_t)(r0 + ty + i) * C + c0 + tx];
    __syncthreads();
#pragma unroll
    for (int i = 0; i < 32; i += 8)
        out[(size_t)(c0 + ty + i) * R + r0 + tx] = f2b(tile[tx][ty + i]);
}

// ---------- LayerNorm: one block per row of 1024, fp32 gamma/beta, bf16 out ----------
template <typename TIN>
__global__ __launch_bounds__(256) void ln_kernel(const TIN* __restrict__ X,
                                                 const float* __restrict__ g,
                                                 const float* __restrict__ b,
                                                 bf16* __restrict__ out)
{
    int row = blockIdx.x;
    int tid = threadIdx.x;
    const TIN* xr = X + (size_t)row * D;
    float v[4];
#pragma unroll
    for (int i = 0; i < 4; ++i) v[i] = loadf(xr + tid + i * 256);

    float s1 = v[0] + v[1] + v[2] + v[3];
    float s2 = v[0]*v[0] + v[1]*v[1] + v[2]*v[2] + v[3]*v[3];
#pragma unroll
    for (int off = 32; off; off >>= 1) {
        s1 += __shfl_xor(s1, off);
        s2 += __shfl_xor(s2, off);
    }
    __shared__ float red[8];
    int lane = tid & 63, w = tid >> 6;
    if (lane == 0) { red[w] = s1; red[4 + w] = s2; }
    __syncthreads();
    s1 = red[0] + red[1] + red[2] + red[3];
    s2 = red[4] + red[5] + red[6] + red[7];

    float mu   = s1 * (1.0f / D);
    float var  = s2 * (1.0f / D) - mu * mu;
    float rstd = rsqrtf(var + 1e-5f);

    bf16* orow = out + (size_t)row * D;
#pragma unroll
    for (int i = 0; i < 4; ++i) {
        int c = tid + i * 256;
        orow[c] = f2b((v[i] - mu) * rstd * g[c] + b[c]);
    }
}

// ---------- MFMA GEMM (unchanged, passing) ----------
template <int RELU, int RES, int OUTF32>
__global__ __launch_bounds__(256) void mfma_gemm(
    const bf16* __restrict__ A, const bf16* __restrict__ Bt,
    const float* __restrict__ bias, const void* __restrict__ resid,
    void* __restrict__ out, int M, int N, int K)
{
    constexpr int LDSK = 40;
    __shared__ __align__(16) unsigned short As[128 * LDSK];
    __shared__ __align__(16) unsigned short Bs[128 * LDSK];

    int tid  = threadIdx.x;
    int m0   = blockIdx.y * 128, n0 = blockIdx.x * 128;
    int lane = tid & 63, wave = tid >> 6;
    int wm = (wave >> 1) * 64, wn = (wave & 1) * 64;
    int c15 = lane & 15, quad = lane >> 4;

    f32x4 acc[4][4] = {};

    int srow = tid >> 1, shalf = tid & 1;
    const bf16* aptr = A  + (size_t)(m0 + srow) * K + shalf * 16;
    const bf16* bptr = Bt + (size_t)(n0 + srow) * K + shalf * 16;
    unsigned short* asl = &As[srow * LDSK + shalf * 16];
    unsigned short* bsl = &Bs[srow * LDSK + shalf * 16];

    for (int k0 = 0; k0 < K; k0 += 32) {
        uint4 a0 = *(const uint4*)(aptr + k0);
        uint4 a1 = *(const uint4*)(aptr + k0 + 8);
        uint4 b0 = *(const uint4*)(bptr + k0);
        uint4 b1 = *(const uint4*)(bptr + k0 + 8);
        __syncthreads();
        *(uint4*)asl       = a0;
        *(uint4*)(asl + 8) = a1;
        *(uint4*)bsl       = b0;
        *(uint4*)(bsl + 8) = b1;
        __syncthreads();

        short8 af[4], bfr[4];
#pragma unroll
        for (int t = 0; t < 4; ++t)
            af[t]  = *(const short8*)&As[(wm + t * 16 + c15) * LDSK + quad * 8];
#pragma unroll
        for (int t = 0; t < 4; ++t)
            bfr[t] = *(const short8*)&Bs[(wn + t * 16 + c15) * LDSK + quad * 8];
#pragma unroll
        for (int mt = 0; mt < 4; ++mt)
#pragma unroll
            for (int nt = 0; nt < 4; ++nt)
                acc[mt][nt] = __builtin_amdgcn_mfma_f32_16x16x32_bf16(
                    af[mt], bfr[nt], acc[mt][nt], 0, 0, 0);
    }

#pragma unroll
    for (int mt = 0; mt < 4; ++mt) {
#pragma unroll
        for (int nt = 0; nt < 4; ++nt) {
            f32x4 v4 = acc[mt][nt];
            int gc = n0 + wn + nt * 16 + c15;
            float bb = bias[gc];
#pragma unroll
            for (int r = 0; r < 4; ++r) {
                int gr = m0 + wm + mt * 16 + quad * 4 + r;
                float v = v4[r] + bb;
                if constexpr (RELU) v = fmaxf(v, 0.0f);
                size_t idx = (size_t)gr * N + gc;
                if constexpr (RES == 1) v += b2f(((const bf16*)resid)[idx]);
                if constexpr (RES == 2) v += ((const float*)resid)[idx];
                if constexpr (OUTF32) ((float*)out)[idx] = v;
                else                  ((bf16*)out)[idx] = f2b(v);
            }
        }
    }
}

// ---------- MFMA flash attention ----------
// Grid: 512 = 32 (b*h) x 16 q-tiles of 128. 4 waves; wave w owns q rows [w*32, w*32+32).
// Per 64-key tile: S = Q K^T (mfma 16x16x32), online softmax (exp2 domain),
// P -> wave-private LDS (C->A layout), O = O*alpha + P V (V transposed in LDS).
// Layouts (m89/m91/m120-verified): A: m=lane&15,k=quad*8+j; B: k=quad*8+j,n=lane&15;
// C/D: row=quad*4+r, col=lane&15.
__global__ __launch_bounds__(256) void flash_attn(const bf16* __restrict__ qkv,
                                                  bf16* __restrict__ ctx)
{
    constexpr int KROW = 72;                 // u16 row stride (144 B, 16B-aligned, breaks pow2)
    constexpr float CSC = 0.18033688011112042f;  // 0.125 * log2(e)

    __shared__ __align__(16) unsigned short Qs[128 * KROW];  // 18 KB; aliased by Ps after Q-frag load
    __shared__ __align__(16) unsigned short Ks[64 * KROW];   //  9 KB  [key][dk]
    __shared__ __align__(16) unsigned short Vt[64 * KROW];   //  9 KB  [dk][key]
    unsigned short* Ps = Qs;

    int bx = blockIdx.x;
    int bh = bx & 31;             // b*h fastest -> L2 spread
    int qi = 15 - (bx >> 5);      // heavy q-tiles first
    int h  = bh & 15, b = bh >> 4;
    int q0 = qi * 128;

    int tid = threadIdx.x, lane = tid & 63, w = tid >> 6;
    int c15 = lane & 15, quad = lane >> 4;

    const bf16* base = qkv + (size_t)b * T * QKVN;

    // --- stage Q tile [128][64] ---
    {
        int row = tid >> 1, half = tid & 1;
        const bf16* src = base + (size_t)(q0 + row) * QKVN + h * 64 + half * 32;
        unsigned short* dst = &Qs[row * KROW + half * 32];
        uint4 v0 = *(const uint4*)(src);
        uint4 v1 = *(const uint4*)(src + 8);
        uint4 v2 = *(const uint4*)(src + 16);
        uint4 v3 = *(const uint4*)(src + 24);
        *(uint4*)(dst)      = v0;
        *(uint4*)(dst + 8)  = v1;
        *(uint4*)(dst + 16) = v2;
        *(uint4*)(dst + 24) = v3;
    }
    __syncthreads();

    // Q A-fragments in registers: wave-private rows [w*32, w*32+32)
    short8 qf[2][2];
#pragma unroll
    for (int mt = 0; mt < 2; ++mt)
#pragma unroll
        for (int s = 0; s < 2; ++s)
            qf[mt][s] = *(const short8*)&Qs[(w * 32 + mt * 16 + c15) * KROW + s * 32 + quad * 8];
    // NOTE: Ps (=Qs) rows [w*32,w*32+32) are only ever touched by wave w from here on.

    f32x4 O[2][4] = {};
    float mrow[2][4], lrow[2][4];
#pragma unroll
    for (int mt = 0; mt < 2; ++mt)
#pragma unroll
        for (int r = 0; r < 4; ++r) { mrow[mt][r] = -1e30f; lrow[mt][r] = 0.0f; }

    int nkt  = q0 / 64 + 2;
    int wqmin = q0 + w * 32;
    int wqmax = wqmin + 31;

    for (int kt = 0; kt < nkt; ++kt) {
        int k0 = kt * 64;
        // ---- global loads (K tile + V tile) ----
        int key = tid >> 2, seg = tid & 3;
        const bf16* ksrc = base + (size_t)(k0 + key) * QKVN + D + h * 64 + seg * 16;
        uint4 kv0 = *(const uint4*)ksrc;
        uint4 kv1 = *(const uint4*)(ksrc + 8);
        int keyp = (tid & 31) * 2, dk0 = (tid >> 5) * 8;
        const bf16* vsrc = base + (size_t)(k0 + keyp) * QKVN + 2 * D + h * 64 + dk0;
        uint4 vv0 = *(const uint4*)vsrc;
        uint4 vv1 = *(const uint4*)(vsrc + QKVN);

        __syncthreads();   // previous iteration's Ks/Vt fragment reads complete
        {
            unsigned short* kd = &Ks[key * KROW + seg * 16];
            *(uint4*)kd       = kv0;
            *(uint4*)(kd + 8) = kv1;
            const unsigned short* lo = (const unsigned short*)&vv0;
            const unsigned short* hi = (const unsigned short*)&vv1;
#pragma unroll
            for (int j = 0; j < 8; ++j) {
                unsigned int pk = (unsigned int)lo[j] | ((unsigned int)hi[j] << 16);
                *(unsigned int*)&Vt[(dk0 + j) * KROW + keyp] = pk;  // Vt[dk][key], key pair packed
            }
        }
        __syncthreads();

        if (k0 <= wqmax) {   // wave-uniform: skip tiles fully above the diagonal
            // ---- S = Q K^T ----
            f32x4 S[2][4] = {};
#pragma unroll
            for (int s = 0; s < 2; ++s)
#pragma unroll
                for (int nt = 0; nt < 4; ++nt) {
                    short8 kf = *(const short8*)&Ks[(nt * 16 + c15) * KROW + s * 32 + quad * 8];
#pragma unroll
                    for (int mt = 0; mt < 2; ++mt)
                        S[mt][nt] = __builtin_amdgcn_mfma_f32_16x16x32_bf16(qf[mt][s], kf, S[mt][nt], 0, 0, 0);
                }

            // ---- scale to exp2 domain + causal mask (diagonal tiles only) ----
            bool diag = (k0 + 63 > wqmin);
#pragma unroll
            for (int mt = 0; mt < 2; ++mt)
#pragma unroll
                for (int nt = 0; nt < 4; ++nt)
#pragma unroll
                    for (int r = 0; r < 4; ++r) {
                        float u = S[mt][nt][r] * CSC;
                        if (diag) {
                            int key_g = k0 + nt * 16 + c15;
                            int q_g   = wqmin + mt * 16 + quad * 4 + r;
                            if (key_g > q_g) u = -1e30f;
                        }
                        S[mt][nt][r] = u;
                    }

            // ---- row max + online-softmax update ----
            float alpha[2][4];
#pragma unroll
            for (int mt = 0; mt < 2; ++mt)
#pragma unroll
                for (int r = 0; r < 4; ++r) {
                    float mx = fmaxf(fmaxf(S[mt][0][r], S[mt][1][r]), fmaxf(S[mt][2][r], S[mt][3][r]));
#pragma unroll
                    for (int off = 1; off < 16; off <<= 1) mx = fmaxf(mx, __shfl_xor(mx, off));
                    float mn = fmaxf(mrow[mt][r], mx);
                    alpha[mt][r] = fast_exp2(mrow[mt][r] - mn);
                    mrow[mt][r] = mn;
                }

            // ---- P = exp2(u - m), row-sum, write P to wave-private LDS ----
#pragma unroll
            for (int mt = 0; mt < 2; ++mt)
#pragma unroll
                for (int r = 0; r < 4; ++r) {
                    float rs = 0.0f;
                    int prow = (w * 32 + mt * 16 + quad * 4 + r) * KROW;
#pragma unroll
                    for (int nt = 0; nt < 4; ++nt) {
                        float p = fast_exp2(S[mt][nt][r] - mrow[mt][r]);
                        rs += p;
                        Ps[prow + nt * 16 + c15] = __bfloat16_as_ushort(f2b(p));
                    }
#pragma unroll
                    for (int off = 1; off < 16; off <<= 1) rs += __shfl_xor(rs, off);
                    lrow[mt][r] = lrow[mt][r] * alpha[mt][r] + rs;
                }

            // ---- rescale O ----
#pragma unroll
            for (int mt = 0; mt < 2; ++mt)
#pragma unroll
                for (int nt = 0; nt < 4; ++nt)
#pragma unroll
                    for (int r = 0; r < 4; ++r)
                        O[mt][nt][r] *= alpha[mt][r];

            // ---- O += P V  (P A-frags from LDS; V B-frags from Vt) ----
#pragma unroll
            for (int s = 0; s < 2; ++s) {
                short8 pa[2];
#pragma unroll
                for (int mt = 0; mt < 2; ++mt)
                    pa[mt] = *(const short8*)&Ps[(w * 32 + mt * 16 + c15) * KROW + s * 32 + quad * 8];
#pragma unroll
                for (int nt = 0; nt < 4; ++nt) {
                    short8 vf = *(const short8*)&Vt[(nt * 16 + c15) * KROW + s * 32 + quad * 8];
#pragma unroll
                    for (int mt = 0; mt < 2; ++mt)
                        O[mt][nt] = __builtin_amdgcn_mfma_f32_16x16x32_bf16(pa[mt], vf, O[mt][nt], 0, 0, 0);
                }
            }
        }
    }

    // ---- epilogue: O /= l, write ctx[row][h*64+dk] ----
#pragma unroll
    for (int mt = 0; mt < 2; ++mt)
#pragma unroll
        for (int r = 0; r < 4; ++r) {
            float inv = 1.0f / lrow[mt][r];
            int grow = b * T + q0 + w * 32 + mt * 16 + quad * 4 + r;
#pragma unroll
            for (int nt = 0; nt < 4; ++nt)
                ctx[(size_t)grow * D + h * 64 + nt * 16 + c15] = f2b(O[mt][nt][r] * inv);
        }
}

extern "C" void kernel_launch(void* const* d_in, const int* in_sizes, int n_in,
                              void* d_out, int out_size, void* d_ws, size_t ws_size,
                              hipStream_t stream)
{
    const float* X    = (const float*)d_in[0];
    const float* Wqkv = (const float*)d_in[1];
    const float* bqkv = (const float*)d_in[2];
    const float* Wo   = (const float*)d_in[3];
    const float* bo   = (const float*)d_in[4];
    const float* W1   = (const float*)d_in[5];
    const float* b1   = (const float*)d_in[6];
    const float* W2   = (const float*)d_in[7];
    const float* b2   = (const float*)d_in[8];
    const float* ln1g = (const float*)d_in[9];
    const float* ln1b = (const float*)d_in[10];
    const float* ln2g = (const float*)d_in[11];
    const float* ln2b = (const float*)d_in[12];
    float* out = (float*)d_out;

    // Workspace (peak 72 MiB):
    char* ws = (char*)d_ws;
    bf16* Wqkv_t = (bf16*)(ws + 0);          // [3072][1024]  6 MiB
    bf16* Wo_t   = (bf16*)(ws + 6291456);    // [1024][1024]  2 MiB
    bf16* W1_t   = (bf16*)(ws + 8388608);    // [4096][1024]  8 MiB
    bf16* W2_t   = (bf16*)(ws + 16777216);   // [1024][4096]  8 MiB
    bf16* Xn     = (bf16*)(ws + 25165824);   // 8 MiB; reused by X1 after step 2
    bf16* X1     = Xn;
    bf16* qkv    = (bf16*)(ws + 33554432);   // 24 MiB; first 8 MiB reused by Xn2 after attn
    bf16* Xn2    = (bf16*)(ws + 33554432);
    bf16* ctx    = (bf16*)(ws + 58720256);   // 8 MiB
    bf16* mid    = (bf16*)(ws + 41943040);   // 32 MiB; ends at 72 MiB

    transpose_cast<<<dim3(QKVN / 32, D / 32), 256, 0, stream>>>(Wqkv, Wqkv_t, D, QKVN);
    transpose_cast<<<dim3(D / 32, D / 32), 256, 0, stream>>>(Wo, Wo_t, D, D);
    transpose_cast<<<dim3(FFNN / 32, D / 32), 256, 0, stream>>>(W1, W1_t, D, FFNN);
    transpose_cast<<<dim3(D / 32, FFNN / 32), 256, 0, stream>>>(W2, W2_t, FFNN, D);

    ln_kernel<float><<<ROWS, 256, 0, stream>>>(X, ln1g, ln1b, Xn);
    mfma_gemm<0, 0, 0><<<dim3(QKVN / 128, ROWS / 128), 256, 0, stream>>>(
        Xn, Wqkv_t, bqkv, nullptr, qkv, ROWS, QKVN, D);
    flash_attn<<<512, 256, 0, stream>>>(qkv, ctx);
    mfma_gemm<0, 2, 0><<<dim3(D / 128, ROWS / 128), 256, 0, stream>>>(
        ctx, Wo_t, bo, X, X1, ROWS, D, D);
    ln_kernel<bf16><<<ROWS, 256, 0, stream>>>(X1, ln2g, ln2b, Xn2);
    mfma_gemm<1, 0, 0><<<dim3(FFNN / 128, ROWS / 128), 256, 0, stream>>>(
        Xn2, W1_t, b1, nullptr, mid, ROWS, FFNN, D);
    mfma_gemm<0, 1, 1><<<dim3(D / 128, ROWS / 128), 256, 0, stream>>>(
        mid, W2_t, b2, X1, out, ROWS, D, FFNN);
}

// Round 6
// 407.999 us; speedup vs baseline: 12.5243x; 1.1323x over previous
//
#include <hip/hip_runtime.h>
#include <hip/hip_bf16.h>

typedef __hip_bfloat16 bf16;
typedef __attribute__((ext_vector_type(8))) short short8;   // 8 bf16 (4 VGPRs)
typedef __attribute__((ext_vector_type(4))) float f32x4;

constexpr int D     = 1024;
constexpr int T     = 2048;
constexpr int BATCH = 2;
constexpr int ROWS  = BATCH * T;   // 4096
constexpr int NH    = 16;
constexpr int DKEY  = 64;
constexpr int QKVN  = 3 * D;       // 3072
constexpr int FFNN  = 4 * D;       // 4096

static __device__ __forceinline__ float b2f(bf16 x) { return __bfloat162float(x); }
static __device__ __forceinline__ bf16  f2b(float x) { return __float2bfloat16(x); }
static __device__ __forceinline__ float loadf(const bf16* p)  { return __bfloat162float(*p); }
static __device__ __forceinline__ float loadf(const float* p) { return *p; }
static __device__ __forceinline__ float fast_exp2(float x) { return __builtin_amdgcn_exp2f(x); }

// ---------- fp32 [R][C] -> bf16 [C][R] transpose + downcast ----------
__global__ __launch_bounds__(256) void transpose_cast(const float* __restrict__ in,
                                                      bf16* __restrict__ out,
                                                      int R, int C)
{
    __shared__ float tile[32][33];
    int c0 = blockIdx.x * 32, r0 = blockIdx.y * 32;
    int tx = threadIdx.x & 31, ty = threadIdx.x >> 5;  // 8 rows per pass
#pragma unroll
    for (int i = 0; i < 32; i += 8)
        tile[ty + i][tx] = in[(size_t)(r0 + ty + i) * C + c0 + tx];
    __syncthreads();
#pragma unroll
    for (int i = 0; i < 32; i += 8)
        out[(size_t)(c0 + ty + i) * R + r0 + tx] = f2b(tile[tx][ty + i]);
}

// ---------- LayerNorm: one block per row of 1024, fp32 gamma/beta, bf16 out ----------
template <typename TIN>
__global__ __launch_bounds__(256) void ln_kernel(const TIN* __restrict__ X,
                                                 const float* __restrict__ g,
                                                 const float* __restrict__ b,
                                                 bf16* __restrict__ out)
{
    int row = blockIdx.x;
    int tid = threadIdx.x;
    const TIN* xr = X + (size_t)row * D;
    float v[4];
#pragma unroll
    for (int i = 0; i < 4; ++i) v[i] = loadf(xr + tid + i * 256);

    float s1 = v[0] + v[1] + v[2] + v[3];
    float s2 = v[0]*v[0] + v[1]*v[1] + v[2]*v[2] + v[3]*v[3];
#pragma unroll
    for (int off = 32; off; off >>= 1) {
        s1 += __shfl_xor(s1, off);
        s2 += __shfl_xor(s2, off);
    }
    __shared__ float red[8];
    int lane = tid & 63, w = tid >> 6;
    if (lane == 0) { red[w] = s1; red[4 + w] = s2; }
    __syncthreads();
    s1 = red[0] + red[1] + red[2] + red[3];
    s2 = red[4] + red[5] + red[6] + red[7];

    float mu   = s1 * (1.0f / D);
    float var  = s2 * (1.0f / D) - mu * mu;
    float rstd = rsqrtf(var + 1e-5f);

    bf16* orow = out + (size_t)row * D;
#pragma unroll
    for (int i = 0; i < 4; ++i) {
        int c = tid + i * 256;
        orow[c] = f2b((v[i] - mu) * rstd * g[c] + b[c]);
    }
}

// ---------- Pipelined MFMA GEMM ----------
// out[M][N] = A[M][K](bf16) @ Bt[N][K]^T + bias (+relu)(+resid)
// BM in {64,128}, BN=128 fixed, BK=32. 4 waves in 2x2; wave tile (BM/2)x64.
// K-loop: register prefetch + double-buffered LDS, ONE barrier per iter:
//   store regs->LDS[k&1]; barrier; issue loads k+1; ds_read+MFMA LDS[k&1].
// Prefetch issued after the barrier so its vmcnt(0) drain is a no-op; load
// latency overlaps the MFMA phase. Buffer re-write is 2 iters (1 barrier)
// after its readers' lgkm drain -> race-free.
template <int BM, int RELU, int RES, int OUTF32>
__global__ __launch_bounds__(256) void mfma_gemm(
    const bf16* __restrict__ A, const bf16* __restrict__ Bt,
    const float* __restrict__ bias, const void* __restrict__ resid,
    void* __restrict__ out, int M, int N, int K)
{
    constexpr int LDSK = 40;       // 32 + 8 pad (80 B stride): 2-way banking max
    constexpr int MT   = BM / 32;  // m-frags per wave (2 or 4)
    __shared__ __align__(16) unsigned short As[2][BM * LDSK];
    __shared__ __align__(16) unsigned short Bs[2][128 * LDSK];

    int tid  = threadIdx.x;
    int m0   = blockIdx.y * BM, n0 = blockIdx.x * 128;
    int lane = tid & 63, wave = tid >> 6;
    int wm = (wave >> 1) * (MT * 16), wn = (wave & 1) * 64;
    int c15 = lane & 15, quad = lane >> 4;

    f32x4 acc[MT][4] = {};

    // staging maps (16 B per uint4)
    int brow = tid >> 1, bseg = (tid & 1) * 16;
    int arow, aseg;
    if constexpr (BM == 128) { arow = tid >> 1; aseg = (tid & 1) * 16; }
    else                     { arow = tid >> 2; aseg = (tid & 3) * 8;  }
    const bf16* aptr = A  + (size_t)(m0 + arow) * K + aseg;
    const bf16* bptr = Bt + (size_t)(n0 + brow) * K + bseg;

    int nk = K >> 5;
    uint4 ra0, ra1, rb0, rb1;
    ra0 = *(const uint4*)(aptr);
    if constexpr (BM == 128) ra1 = *(const uint4*)(aptr + 8);
    rb0 = *(const uint4*)(bptr);
    rb1 = *(const uint4*)(bptr + 8);

    for (int kt = 0; kt < nk; ++kt) {
        int buf = kt & 1;
        {
            unsigned short* asl = &As[buf][arow * LDSK + aseg];
            unsigned short* bsl = &Bs[buf][brow * LDSK + bseg];
            *(uint4*)asl = ra0;
            if constexpr (BM == 128) *(uint4*)(asl + 8) = ra1;
            *(uint4*)bsl       = rb0;
            *(uint4*)(bsl + 8) = rb1;
        }
        __syncthreads();
        if (kt + 1 < nk) {                    // prefetch next K-tile (post-barrier)
            int ko = (kt + 1) * 32;
            ra0 = *(const uint4*)(aptr + ko);
            if constexpr (BM == 128) ra1 = *(const uint4*)(aptr + ko + 8);
            rb0 = *(const uint4*)(bptr + ko);
            rb1 = *(const uint4*)(bptr + ko + 8);
        }
        short8 af[MT], bfr[4];
#pragma unroll
        for (int t = 0; t < MT; ++t)
            af[t]  = *(const short8*)&As[buf][(wm + t * 16 + c15) * LDSK + quad * 8];
#pragma unroll
        for (int t = 0; t < 4; ++t)
            bfr[t] = *(const short8*)&Bs[buf][(wn + t * 16 + c15) * LDSK + quad * 8];
#pragma unroll
        for (int mt = 0; mt < MT; ++mt)
#pragma unroll
            for (int nt = 0; nt < 4; ++nt)
                acc[mt][nt] = __builtin_amdgcn_mfma_f32_16x16x32_bf16(
                    af[mt], bfr[nt], acc[mt][nt], 0, 0, 0);
    }

#pragma unroll
    for (int mt = 0; mt < MT; ++mt) {
#pragma unroll
        for (int nt = 0; nt < 4; ++nt) {
            f32x4 v4 = acc[mt][nt];
            int gc = n0 + wn + nt * 16 + c15;
            float bb = bias[gc];
#pragma unroll
            for (int r = 0; r < 4; ++r) {
                int gr = m0 + wm + mt * 16 + quad * 4 + r;
                float v = v4[r] + bb;
                if constexpr (RELU) v = fmaxf(v, 0.0f);
                size_t idx = (size_t)gr * N + gc;
                if constexpr (RES == 1) v += b2f(((const bf16*)resid)[idx]);
                if constexpr (RES == 2) v += ((const float*)resid)[idx];
                if constexpr (OUTF32) ((float*)out)[idx] = v;
                else                  ((bf16*)out)[idx] = f2b(v);
            }
        }
    }
}

// ---------- MFMA flash attention (unchanged, passing) ----------
__global__ __launch_bounds__(256) void flash_attn(const bf16* __restrict__ qkv,
                                                  bf16* __restrict__ ctx)
{
    constexpr int KROW = 72;
    constexpr float CSC = 0.18033688011112042f;  // 0.125 * log2(e)

    __shared__ __align__(16) unsigned short Qs[128 * KROW];
    __shared__ __align__(16) unsigned short Ks[64 * KROW];
    __shared__ __align__(16) unsigned short Vt[64 * KROW];
    unsigned short* Ps = Qs;

    int bx = blockIdx.x;
    int bh = bx & 31;
    int qi = 15 - (bx >> 5);
    int h  = bh & 15, b = bh >> 4;
    int q0 = qi * 128;

    int tid = threadIdx.x, lane = tid & 63, w = tid >> 6;
    int c15 = lane & 15, quad = lane >> 4;

    const bf16* base = qkv + (size_t)b * T * QKVN;

    {
        int row = tid >> 1, half = tid & 1;
        const bf16* src = base + (size_t)(q0 + row) * QKVN + h * 64 + half * 32;
        unsigned short* dst = &Qs[row * KROW + half * 32];
        uint4 v0 = *(const uint4*)(src);
        uint4 v1 = *(const uint4*)(src + 8);
        uint4 v2 = *(const uint4*)(src + 16);
        uint4 v3 = *(const uint4*)(src + 24);
        *(uint4*)(dst)      = v0;
        *(uint4*)(dst + 8)  = v1;
        *(uint4*)(dst + 16) = v2;
        *(uint4*)(dst + 24) = v3;
    }
    __syncthreads();

    short8 qf[2][2];
#pragma unroll
    for (int mt = 0; mt < 2; ++mt)
#pragma unroll
        for (int s = 0; s < 2; ++s)
            qf[mt][s] = *(const short8*)&Qs[(w * 32 + mt * 16 + c15) * KROW + s * 32 + quad * 8];

    f32x4 O[2][4] = {};
    float mrow[2][4], lrow[2][4];
#pragma unroll
    for (int mt = 0; mt < 2; ++mt)
#pragma unroll
        for (int r = 0; r < 4; ++r) { mrow[mt][r] = -1e30f; lrow[mt][r] = 0.0f; }

    int nkt  = q0 / 64 + 2;
    int wqmin = q0 + w * 32;
    int wqmax = wqmin + 31;

    for (int kt = 0; kt < nkt; ++kt) {
        int k0 = kt * 64;
        int key = tid >> 2, seg = tid & 3;
        const bf16* ksrc = base + (size_t)(k0 + key) * QKVN + D + h * 64 + seg * 16;
        uint4 kv0 = *(const uint4*)ksrc;
        uint4 kv1 = *(const uint4*)(ksrc + 8);
        int keyp = (tid & 31) * 2, dk0 = (tid >> 5) * 8;
        const bf16* vsrc = base + (size_t)(k0 + keyp) * QKVN + 2 * D + h * 64 + dk0;
        uint4 vv0 = *(const uint4*)vsrc;
        uint4 vv1 = *(const uint4*)(vsrc + QKVN);

        __syncthreads();
        {
            unsigned short* kd = &Ks[key * KROW + seg * 16];
            *(uint4*)kd       = kv0;
            *(uint4*)(kd + 8) = kv1;
            const unsigned short* lo = (const unsigned short*)&vv0;
            const unsigned short* hi = (const unsigned short*)&vv1;
#pragma unroll
            for (int j = 0; j < 8; ++j) {
                unsigned int pk = (unsigned int)lo[j] | ((unsigned int)hi[j] << 16);
                *(unsigned int*)&Vt[(dk0 + j) * KROW + keyp] = pk;
            }
        }
        __syncthreads();

        if (k0 <= wqmax) {
            f32x4 S[2][4] = {};
#pragma unroll
            for (int s = 0; s < 2; ++s)
#pragma unroll
                for (int nt = 0; nt < 4; ++nt) {
                    short8 kf = *(const short8*)&Ks[(nt * 16 + c15) * KROW + s * 32 + quad * 8];
#pragma unroll
                    for (int mt = 0; mt < 2; ++mt)
                        S[mt][nt] = __builtin_amdgcn_mfma_f32_16x16x32_bf16(qf[mt][s], kf, S[mt][nt], 0, 0, 0);
                }

            bool diag = (k0 + 63 > wqmin);
#pragma unroll
            for (int mt = 0; mt < 2; ++mt)
#pragma unroll
                for (int nt = 0; nt < 4; ++nt)
#pragma unroll
                    for (int r = 0; r < 4; ++r) {
                        float u = S[mt][nt][r] * CSC;
                        if (diag) {
                            int key_g = k0 + nt * 16 + c15;
                            int q_g   = wqmin + mt * 16 + quad * 4 + r;
                            if (key_g > q_g) u = -1e30f;
                        }
                        S[mt][nt][r] = u;
                    }

            float alpha[2][4];
#pragma unroll
            for (int mt = 0; mt < 2; ++mt)
#pragma unroll
                for (int r = 0; r < 4; ++r) {
                    float mx = fmaxf(fmaxf(S[mt][0][r], S[mt][1][r]), fmaxf(S[mt][2][r], S[mt][3][r]));
#pragma unroll
                    for (int off = 1; off < 16; off <<= 1) mx = fmaxf(mx, __shfl_xor(mx, off));
                    float mn = fmaxf(mrow[mt][r], mx);
                    alpha[mt][r] = fast_exp2(mrow[mt][r] - mn);
                    mrow[mt][r] = mn;
                }

#pragma unroll
            for (int mt = 0; mt < 2; ++mt)
#pragma unroll
                for (int r = 0; r < 4; ++r) {
                    float rs = 0.0f;
                    int prow = (w * 32 + mt * 16 + quad * 4 + r) * KROW;
#pragma unroll
                    for (int nt = 0; nt < 4; ++nt) {
                        float p = fast_exp2(S[mt][nt][r] - mrow[mt][r]);
                        rs += p;
                        Ps[prow + nt * 16 + c15] = __bfloat16_as_ushort(f2b(p));
                    }
#pragma unroll
                    for (int off = 1; off < 16; off <<= 1) rs += __shfl_xor(rs, off);
                    lrow[mt][r] = lrow[mt][r] * alpha[mt][r] + rs;
                }

#pragma unroll
            for (int mt = 0; mt < 2; ++mt)
#pragma unroll
                for (int nt = 0; nt < 4; ++nt)
#pragma unroll
                    for (int r = 0; r < 4; ++r)
                        O[mt][nt][r] *= alpha[mt][r];

#pragma unroll
            for (int s = 0; s < 2; ++s) {
                short8 pa[2];
#pragma unroll
                for (int mt = 0; mt < 2; ++mt)
                    pa[mt] = *(const short8*)&Ps[(w * 32 + mt * 16 + c15) * KROW + s * 32 + quad * 8];
#pragma unroll
                for (int nt = 0; nt < 4; ++nt) {
                    short8 vf = *(const short8*)&Vt[(nt * 16 + c15) * KROW + s * 32 + quad * 8];
#pragma unroll
                    for (int mt = 0; mt < 2; ++mt)
                        O[mt][nt] = __builtin_amdgcn_mfma_f32_16x16x32_bf16(pa[mt], vf, O[mt][nt], 0, 0, 0);
                }
            }
        }
    }

#pragma unroll
    for (int mt = 0; mt < 2; ++mt)
#pragma unroll
        for (int r = 0; r < 4; ++r) {
            float inv = 1.0f / lrow[mt][r];
            int grow = b * T + q0 + w * 32 + mt * 16 + quad * 4 + r;
#pragma unroll
            for (int nt = 0; nt < 4; ++nt)
                ctx[(size_t)grow * D + h * 64 + nt * 16 + c15] = f2b(O[mt][nt][r] * inv);
        }
}

extern "C" void kernel_launch(void* const* d_in, const int* in_sizes, int n_in,
                              void* d_out, int out_size, void* d_ws, size_t ws_size,
                              hipStream_t stream)
{
    const float* X    = (const float*)d_in[0];
    const float* Wqkv = (const float*)d_in[1];
    const float* bqkv = (const float*)d_in[2];
    const float* Wo   = (const float*)d_in[3];
    const float* bo   = (const float*)d_in[4];
    const float* W1   = (const float*)d_in[5];
    const float* b1   = (const float*)d_in[6];
    const float* W2   = (const float*)d_in[7];
    const float* b2   = (const float*)d_in[8];
    const float* ln1g = (const float*)d_in[9];
    const float* ln1b = (const float*)d_in[10];
    const float* ln2g = (const float*)d_in[11];
    const float* ln2b = (const float*)d_in[12];
    float* out = (float*)d_out;

    // Workspace (peak 72 MiB):
    char* ws = (char*)d_ws;
    bf16* Wqkv_t = (bf16*)(ws + 0);          // [3072][1024]  6 MiB
    bf16* Wo_t   = (bf16*)(ws + 6291456);    // [1024][1024]  2 MiB
    bf16* W1_t   = (bf16*)(ws + 8388608);    // [4096][1024]  8 MiB
    bf16* W2_t   = (bf16*)(ws + 16777216);   // [1024][4096]  8 MiB
    bf16* Xn     = (bf16*)(ws + 25165824);   // 8 MiB; reused by X1 after step 2
    bf16* X1     = Xn;
    bf16* qkv    = (bf16*)(ws + 33554432);   // 24 MiB; first 8 MiB reused by Xn2 after attn
    bf16* Xn2    = (bf16*)(ws + 33554432);
    bf16* ctx    = (bf16*)(ws + 58720256);   // 8 MiB
    bf16* mid    = (bf16*)(ws + 41943040);   // 32 MiB; ends at 72 MiB

    transpose_cast<<<dim3(QKVN / 32, D / 32), 256, 0, stream>>>(Wqkv, Wqkv_t, D, QKVN);
    transpose_cast<<<dim3(D / 32, D / 32), 256, 0, stream>>>(Wo, Wo_t, D, D);
    transpose_cast<<<dim3(FFNN / 32, D / 32), 256, 0, stream>>>(W1, W1_t, D, FFNN);
    transpose_cast<<<dim3(D / 32, FFNN / 32), 256, 0, stream>>>(W2, W2_t, FFNN, D);

    ln_kernel<float><<<ROWS, 256, 0, stream>>>(X, ln1g, ln1b, Xn);
    // QKV: 128x128 tiles, grid 24x32 = 768 blocks (3/CU)
    mfma_gemm<128, 0, 0, 0><<<dim3(QKVN / 128, ROWS / 128), 256, 0, stream>>>(
        Xn, Wqkv_t, bqkv, nullptr, qkv, ROWS, QKVN, D);
    flash_attn<<<512, 256, 0, stream>>>(qkv, ctx);
    // Wo: 64x128 tiles, grid 8x64 = 512 blocks (2/CU)
    mfma_gemm<64, 0, 2, 0><<<dim3(D / 128, ROWS / 64), 256, 0, stream>>>(
        ctx, Wo_t, bo, X, X1, ROWS, D, D);
    ln_kernel<bf16><<<ROWS, 256, 0, stream>>>(X1, ln2g, ln2b, Xn2);
    // FFN1: 128x128 tiles, grid 32x32 = 1024 blocks (4/CU)
    mfma_gemm<128, 1, 0, 0><<<dim3(FFNN / 128, ROWS / 128), 256, 0, stream>>>(
        Xn2, W1_t, b1, nullptr, mid, ROWS, FFNN, D);
    // FFN2: 64x128 tiles, K=4096, grid 8x64 = 512 blocks (2/CU)
    mfma_gemm<64, 0, 1, 1><<<dim3(D / 128, ROWS / 64), 256, 0, stream>>>(
        mid, W2_t, b2, X1, out, ROWS, D, FFNN);
}

// Round 7
// 375.272 us; speedup vs baseline: 13.6165x; 1.0872x over previous
//
#include <hip/hip_runtime.h>
#include <hip/hip_bf16.h>

typedef __hip_bfloat16 bf16;
typedef __attribute__((ext_vector_type(8))) short short8;   // 8 bf16 (4 VGPRs)
typedef __attribute__((ext_vector_type(4))) float f32x4;

constexpr int D     = 1024;
constexpr int T     = 2048;
constexpr int BATCH = 2;
constexpr int ROWS  = BATCH * T;   // 4096
constexpr int NH    = 16;
constexpr int DKEY  = 64;
constexpr int QKVN  = 3 * D;       // 3072
constexpr int FFNN  = 4 * D;       // 4096

static __device__ __forceinline__ float b2f(bf16 x) { return __bfloat162float(x); }
static __device__ __forceinline__ bf16  f2b(float x) { return __float2bfloat16(x); }
static __device__ __forceinline__ float loadf(const bf16* p)  { return __bfloat162float(*p); }
static __device__ __forceinline__ float loadf(const float* p) { return *p; }
static __device__ __forceinline__ float fast_exp2(float x) { return __builtin_amdgcn_exp2f(x); }
static __device__ __forceinline__ unsigned short f2bu(float x) {
    return __bfloat16_as_ushort(__float2bfloat16(x));
}

// ---------- fp32 [R][C] -> bf16 [C][R] transpose + downcast ----------
__global__ __launch_bounds__(256) void transpose_cast(const float* __restrict__ in,
                                                      bf16* __restrict__ out,
                                                      int R, int C)
{
    __shared__ float tile[32][33];
    int c0 = blockIdx.x * 32, r0 = blockIdx.y * 32;
    int tx = threadIdx.x & 31, ty = threadIdx.x >> 5;  // 8 rows per pass
#pragma unroll
    for (int i = 0; i < 32; i += 8)
        tile[ty + i][tx] = in[(size_t)(r0 + ty + i) * C + c0 + tx];
    __syncthreads();
#pragma unroll
    for (int i = 0; i < 32; i += 8)
        out[(size_t)(c0 + ty + i) * R + r0 + tx] = f2b(tile[tx][ty + i]);
}

// ---------- LayerNorm: one block per row of 1024, fp32 gamma/beta, bf16 out ----------
template <typename TIN>
__global__ __launch_bounds__(256) void ln_kernel(const TIN* __restrict__ X,
                                                 const float* __restrict__ g,
                                                 const float* __restrict__ b,
                                                 bf16* __restrict__ out)
{
    int row = blockIdx.x;
    int tid = threadIdx.x;
    const TIN* xr = X + (size_t)row * D;
    float v[4];
#pragma unroll
    for (int i = 0; i < 4; ++i) v[i] = loadf(xr + tid + i * 256);

    float s1 = v[0] + v[1] + v[2] + v[3];
    float s2 = v[0]*v[0] + v[1]*v[1] + v[2]*v[2] + v[3]*v[3];
#pragma unroll
    for (int off = 32; off; off >>= 1) {
        s1 += __shfl_xor(s1, off);
        s2 += __shfl_xor(s2, off);
    }
    __shared__ float red[8];
    int lane = tid & 63, w = tid >> 6;
    if (lane == 0) { red[w] = s1; red[4 + w] = s2; }
    __syncthreads();
    s1 = red[0] + red[1] + red[2] + red[3];
    s2 = red[4] + red[5] + red[6] + red[7];

    float mu   = s1 * (1.0f / D);
    float var  = s2 * (1.0f / D) - mu * mu;
    float rstd = rsqrtf(var + 1e-5f);

    bf16* orow = out + (size_t)row * D;
#pragma unroll
    for (int i = 0; i < 4; ++i) {
        int c = tid + i * 256;
        orow[c] = f2b((v[i] - mu) * rstd * g[c] + b[c]);
    }
}

// ---------- Pipelined MFMA GEMM (unchanged from round 6, passing) ----------
template <int BM, int RELU, int RES, int OUTF32>
__global__ __launch_bounds__(256) void mfma_gemm(
    const bf16* __restrict__ A, const bf16* __restrict__ Bt,
    const float* __restrict__ bias, const void* __restrict__ resid,
    void* __restrict__ out, int M, int N, int K)
{
    constexpr int LDSK = 40;       // 32 + 8 pad (80 B stride)
    constexpr int MT   = BM / 32;  // m-frags per wave (2 or 4)
    __shared__ __align__(16) unsigned short As[2][BM * LDSK];
    __shared__ __align__(16) unsigned short Bs[2][128 * LDSK];

    int tid  = threadIdx.x;
    int m0   = blockIdx.y * BM, n0 = blockIdx.x * 128;
    int lane = tid & 63, wave = tid >> 6;
    int wm = (wave >> 1) * (MT * 16), wn = (wave & 1) * 64;
    int c15 = lane & 15, quad = lane >> 4;

    f32x4 acc[MT][4] = {};

    int brow = tid >> 1, bseg = (tid & 1) * 16;
    int arow, aseg;
    if constexpr (BM == 128) { arow = tid >> 1; aseg = (tid & 1) * 16; }
    else                     { arow = tid >> 2; aseg = (tid & 3) * 8;  }
    const bf16* aptr = A  + (size_t)(m0 + arow) * K + aseg;
    const bf16* bptr = Bt + (size_t)(n0 + brow) * K + bseg;

    int nk = K >> 5;
    uint4 ra0, ra1, rb0, rb1;
    ra0 = *(const uint4*)(aptr);
    if constexpr (BM == 128) ra1 = *(const uint4*)(aptr + 8);
    rb0 = *(const uint4*)(bptr);
    rb1 = *(const uint4*)(bptr + 8);

    for (int kt = 0; kt < nk; ++kt) {
        int buf = kt & 1;
        {
            unsigned short* asl = &As[buf][arow * LDSK + aseg];
            unsigned short* bsl = &Bs[buf][brow * LDSK + bseg];
            *(uint4*)asl = ra0;
            if constexpr (BM == 128) *(uint4*)(asl + 8) = ra1;
            *(uint4*)bsl       = rb0;
            *(uint4*)(bsl + 8) = rb1;
        }
        __syncthreads();
        if (kt + 1 < nk) {
            int ko = (kt + 1) * 32;
            ra0 = *(const uint4*)(aptr + ko);
            if constexpr (BM == 128) ra1 = *(const uint4*)(aptr + ko + 8);
            rb0 = *(const uint4*)(bptr + ko);
            rb1 = *(const uint4*)(bptr + ko + 8);
        }
        short8 af[MT], bfr[4];
#pragma unroll
        for (int t = 0; t < MT; ++t)
            af[t]  = *(const short8*)&As[buf][(wm + t * 16 + c15) * LDSK + quad * 8];
#pragma unroll
        for (int t = 0; t < 4; ++t)
            bfr[t] = *(const short8*)&Bs[buf][(wn + t * 16 + c15) * LDSK + quad * 8];
#pragma unroll
        for (int mt = 0; mt < MT; ++mt)
#pragma unroll
            for (int nt = 0; nt < 4; ++nt)
                acc[mt][nt] = __builtin_amdgcn_mfma_f32_16x16x32_bf16(
                    af[mt], bfr[nt], acc[mt][nt], 0, 0, 0);
    }

#pragma unroll
    for (int mt = 0; mt < MT; ++mt) {
#pragma unroll
        for (int nt = 0; nt < 4; ++nt) {
            f32x4 v4 = acc[mt][nt];
            int gc = n0 + wn + nt * 16 + c15;
            float bb = bias[gc];
#pragma unroll
            for (int r = 0; r < 4; ++r) {
                int gr = m0 + wm + mt * 16 + quad * 4 + r;
                float v = v4[r] + bb;
                if constexpr (RELU) v = fmaxf(v, 0.0f);
                size_t idx = (size_t)gr * N + gc;
                if constexpr (RES == 1) v += b2f(((const bf16*)resid)[idx]);
                if constexpr (RES == 2) v += ((const float*)resid)[idx];
                if constexpr (OUTF32) ((float*)out)[idx] = v;
                else                  ((bf16*)out)[idx] = f2b(v);
            }
        }
    }
}

// ---------- MFMA flash attention, transposed orientation + fixed-shift softmax ----------
// S^T = K Q^T  (A=K from Ks[key][dk], B=Q from Qs[qrow][dk]) -> lane holds 4 consecutive keys
// P = exp2(S*CSC - 12)  (softmax shift-invariant; no running max / alpha / rescale)
// P^T stored to Pt[qrow][key] via b64 writes; O^T = V^T P^T (A=Vt[dk][key], B=Pt)
// l = ones-MFMA row sums accumulated across tiles.
__global__ __launch_bounds__(256) void flash_attn(const bf16* __restrict__ qkv,
                                                  bf16* __restrict__ ctx)
{
    constexpr int KROW = 72;
    constexpr float CSC = 0.18033688011112042f;  // 0.125 * log2(e)
    constexpr float MSH = 12.0f;                 // fixed exp2-domain shift

    __shared__ __align__(16) unsigned short Qs[128 * KROW];  // aliased by Pt after qf cache
    __shared__ __align__(16) unsigned short Ks[64 * KROW];   // [key][dk]
    __shared__ __align__(16) unsigned short Vt[64 * KROW];   // [dk][key]
    unsigned short* Pt = Qs;                                 // [qrow][key], wave-private rows

    int bx = blockIdx.x;
    int bh = bx & 31;
    int qi = 15 - (bx >> 5);      // heavy q-tiles first
    int h  = bh & 15, b = bh >> 4;
    int q0 = qi * 128;

    int tid = threadIdx.x, lane = tid & 63, w = tid >> 6;
    int c15 = lane & 15, quad = lane >> 4;

    const bf16* base = qkv + (size_t)b * T * QKVN;

    // --- stage Q tile [128][64] ---
    {
        int row = tid >> 1, half = tid & 1;
        const bf16* src = base + (size_t)(q0 + row) * QKVN + h * 64 + half * 32;
        unsigned short* dst = &Qs[row * KROW + half * 32];
        uint4 v0 = *(const uint4*)(src);
        uint4 v1 = *(const uint4*)(src + 8);
        uint4 v2 = *(const uint4*)(src + 16);
        uint4 v3 = *(const uint4*)(src + 24);
        *(uint4*)(dst)      = v0;
        *(uint4*)(dst + 8)  = v1;
        *(uint4*)(dst + 16) = v2;
        *(uint4*)(dst + 24) = v3;
    }
    __syncthreads();

    // Q B-fragments cached in registers (wave-private rows [w*32, w*32+32))
    short8 qf[2][2];
#pragma unroll
    for (int qt = 0; qt < 2; ++qt)
#pragma unroll
        for (int s = 0; s < 2; ++s)
            qf[qt][s] = *(const short8*)&Qs[(w * 32 + qt * 16 + c15) * KROW + s * 32 + quad * 8];

    short8 ones;
#pragma unroll
    for (int i = 0; i < 8; ++i) ones[i] = (short)0x3F80;  // bf16 1.0

    f32x4 Ot[4][2] = {};   // [dt][qt] : O^T[dk][qrow]
    f32x4 lacc[2]  = {};   // row sums per qt

    int nkt   = q0 / 64 + 2;
    int wqmin = q0 + w * 32;
    int wqmax = wqmin + 31;

    for (int kt = 0; kt < nkt; ++kt) {
        int k0 = kt * 64;
        // ---- global loads (K tile + V tile) ----
        int key = tid >> 2, seg = tid & 3;
        const bf16* ksrc = base + (size_t)(k0 + key) * QKVN + D + h * 64 + seg * 16;
        uint4 kv0 = *(const uint4*)ksrc;
        uint4 kv1 = *(const uint4*)(ksrc + 8);
        int keyp = (tid & 31) * 2, dk0 = (tid >> 5) * 8;
        const bf16* vsrc = base + (size_t)(k0 + keyp) * QKVN + 2 * D + h * 64 + dk0;
        uint4 vv0 = *(const uint4*)vsrc;
        uint4 vv1 = *(const uint4*)(vsrc + QKVN);

        __syncthreads();   // previous iteration's Ks/Vt fragment reads complete
        {
            unsigned short* kd = &Ks[key * KROW + seg * 16];
            *(uint4*)kd       = kv0;
            *(uint4*)(kd + 8) = kv1;
            const unsigned short* lo = (const unsigned short*)&vv0;
            const unsigned short* hi = (const unsigned short*)&vv1;
#pragma unroll
            for (int j = 0; j < 8; ++j) {
                unsigned int pk = (unsigned int)lo[j] | ((unsigned int)hi[j] << 16);
                *(unsigned int*)&Vt[(dk0 + j) * KROW + keyp] = pk;  // Vt[dk][key]
            }
        }
        __syncthreads();

        if (k0 <= wqmax) {   // wave-uniform: skip tiles fully above the diagonal
            // ---- S^T = K Q^T : St[ktm][qt], lane holds key=ktm*16+quad*4+r, qrow=qt*16+c15
            f32x4 St[4][2] = {};
#pragma unroll
            for (int s = 0; s < 2; ++s)
#pragma unroll
                for (int ktm = 0; ktm < 4; ++ktm) {
                    short8 kf = *(const short8*)&Ks[(ktm * 16 + c15) * KROW + s * 32 + quad * 8];
#pragma unroll
                    for (int qt = 0; qt < 2; ++qt)
                        St[ktm][qt] = __builtin_amdgcn_mfma_f32_16x16x32_bf16(
                            kf, qf[qt][s], St[ktm][qt], 0, 0, 0);
                }

            // ---- P = exp2(S*CSC - MSH) (+ causal mask on diagonal tiles), store to Pt ----
            bool diag = (k0 + 63 > wqmin);
#pragma unroll
            for (int ktm = 0; ktm < 4; ++ktm)
#pragma unroll
                for (int qt = 0; qt < 2; ++qt) {
                    ushort4 pk;
                    int q_g = wqmin + qt * 16 + c15;
#pragma unroll
                    for (int r = 0; r < 4; ++r) {
                        float p = fast_exp2(fmaf(St[ktm][qt][r], CSC, -MSH));
                        if (diag && (k0 + ktm * 16 + quad * 4 + r > q_g)) p = 0.0f;
                        ((unsigned short*)&pk)[r] = f2bu(p);
                    }
                    *(ushort4*)&Pt[(w * 32 + qt * 16 + c15) * KROW + ktm * 16 + quad * 4] = pk;
                }

            // ---- O^T += V^T P^T ; l += ones . P^T  (wave-private, no barrier) ----
#pragma unroll
            for (int s = 0; s < 2; ++s) {
                short8 pf[2];
#pragma unroll
                for (int qt = 0; qt < 2; ++qt)
                    pf[qt] = *(const short8*)&Pt[(w * 32 + qt * 16 + c15) * KROW + s * 32 + quad * 8];
#pragma unroll
                for (int qt = 0; qt < 2; ++qt)
                    lacc[qt] = __builtin_amdgcn_mfma_f32_16x16x32_bf16(ones, pf[qt], lacc[qt], 0, 0, 0);
#pragma unroll
                for (int dt = 0; dt < 4; ++dt) {
                    short8 vf = *(const short8*)&Vt[(dt * 16 + c15) * KROW + s * 32 + quad * 8];
#pragma unroll
                    for (int qt = 0; qt < 2; ++qt)
                        Ot[dt][qt] = __builtin_amdgcn_mfma_f32_16x16x32_bf16(
                            vf, pf[qt], Ot[dt][qt], 0, 0, 0);
                }
            }
        }
    }

    // ---- epilogue: ctx[qrow][h*64+dk] = O^T / l, packed 8 B stores ----
#pragma unroll
    for (int qt = 0; qt < 2; ++qt) {
        float inv = 1.0f / lacc[qt][0];
        int grow = b * T + q0 + w * 32 + qt * 16 + c15;
        bf16* dst = ctx + (size_t)grow * D + h * 64 + quad * 4;
#pragma unroll
        for (int dt = 0; dt < 4; ++dt) {
            ushort4 pk;
#pragma unroll
            for (int r = 0; r < 4; ++r)
                ((unsigned short*)&pk)[r] = f2bu(Ot[dt][qt][r] * inv);
            *(ushort4*)(dst + dt * 16) = pk;
        }
    }
}

extern "C" void kernel_launch(void* const* d_in, const int* in_sizes, int n_in,
                              void* d_out, int out_size, void* d_ws, size_t ws_size,
                              hipStream_t stream)
{
    const float* X    = (const float*)d_in[0];
    const float* Wqkv = (const float*)d_in[1];
    const float* bqkv = (const float*)d_in[2];
    const float* Wo   = (const float*)d_in[3];
    const float* bo   = (const float*)d_in[4];
    const float* W1   = (const float*)d_in[5];
    const float* b1   = (const float*)d_in[6];
    const float* W2   = (const float*)d_in[7];
    const float* b2   = (const float*)d_in[8];
    const float* ln1g = (const float*)d_in[9];
    const float* ln1b = (const float*)d_in[10];
    const float* ln2g = (const float*)d_in[11];
    const float* ln2b = (const float*)d_in[12];
    float* out = (float*)d_out;

    // Workspace (peak 72 MiB):
    char* ws = (char*)d_ws;
    bf16* Wqkv_t = (bf16*)(ws + 0);          // [3072][1024]  6 MiB
    bf16* Wo_t   = (bf16*)(ws + 6291456);    // [1024][1024]  2 MiB
    bf16* W1_t   = (bf16*)(ws + 8388608);    // [4096][1024]  8 MiB
    bf16* W2_t   = (bf16*)(ws + 16777216);   // [1024][4096]  8 MiB
    bf16* Xn     = (bf16*)(ws + 25165824);   // 8 MiB; reused by X1 after step 2
    bf16* X1     = Xn;
    bf16* qkv    = (bf16*)(ws + 33554432);   // 24 MiB; first 8 MiB reused by Xn2 after attn
    bf16* Xn2    = (bf16*)(ws + 33554432);
    bf16* ctx    = (bf16*)(ws + 58720256);   // 8 MiB
    bf16* mid    = (bf16*)(ws + 41943040);   // 32 MiB; ends at 72 MiB

    transpose_cast<<<dim3(QKVN / 32, D / 32), 256, 0, stream>>>(Wqkv, Wqkv_t, D, QKVN);
    transpose_cast<<<dim3(D / 32, D / 32), 256, 0, stream>>>(Wo, Wo_t, D, D);
    transpose_cast<<<dim3(FFNN / 32, D / 32), 256, 0, stream>>>(W1, W1_t, D, FFNN);
    transpose_cast<<<dim3(D / 32, FFNN / 32), 256, 0, stream>>>(W2, W2_t, FFNN, D);

    ln_kernel<float><<<ROWS, 256, 0, stream>>>(X, ln1g, ln1b, Xn);
    mfma_gemm<128, 0, 0, 0><<<dim3(QKVN / 128, ROWS / 128), 256, 0, stream>>>(
        Xn, Wqkv_t, bqkv, nullptr, qkv, ROWS, QKVN, D);
    flash_attn<<<512, 256, 0, stream>>>(qkv, ctx);
    mfma_gemm<64, 0, 2, 0><<<dim3(D / 128, ROWS / 64), 256, 0, stream>>>(
        ctx, Wo_t, bo, X, X1, ROWS, D, D);
    ln_kernel<bf16><<<ROWS, 256, 0, stream>>>(X1, ln2g, ln2b, Xn2);
    mfma_gemm<128, 1, 0, 0><<<dim3(FFNN / 128, ROWS / 128), 256, 0, stream>>>(
        Xn2, W1_t, b1, nullptr, mid, ROWS, FFNN, D);
    mfma_gemm<64, 0, 1, 1><<<dim3(D / 128, ROWS / 64), 256, 0, stream>>>(
        mid, W2_t, b2, X1, out, ROWS, D, FFNN);
}